// Round 1
// baseline (1055.151 us; speedup 1.0000x reference)
//
#include <hip/hip_runtime.h>
#include <cstdint>

namespace {

constexpr int kB = 128;   // batch
constexpr int kQ = 32;    // query len
constexpr int kD = 512;   // doc len
constexpr int kE = 300;   // embed dim
constexpr int kC = 128;   // conv channels
constexpr int kK = 11;    // RBF kernels

// workspace layout (float offsets)
constexpr size_t WT1   = 0;         // [320][128]  (k=1, K' padded to 32*10)
constexpr size_t WT2   = 40960;     // [640][128]  (k=2)
constexpr size_t WT3   = 122880;    // [960][128]  (k=3)
constexpr size_t BIAS3 = 245760;    // [3][128]
constexpr size_t QN    = 246144;    // [3][B][C][Q] normalized q conv outputs (transposed)
constexpr size_t DN    = 1819008;   // [3][B][C][D]
constexpr size_t PKQ   = 26984832;  // [9][B][Q][11]
// total 27390336 floats = 109.6 MB

// ---------------- weight transpose / pad + bias pack ----------------
__global__ __launch_bounds__(256) void prep_kernel(
    const float* __restrict__ w1, const float* __restrict__ w2, const float* __restrict__ w3,
    const float* __restrict__ b1, const float* __restrict__ b2, const float* __restrict__ b3,
    float* __restrict__ ws)
{
  int i = blockIdx.x * 256 + threadIdx.x;
  if (i < 320*128) {
    int m = i >> 7, c = i & 127;                    // K=1: m == e
    ws[WT1 + i] = (m < kE) ? w1[c*kE + m] : 0.f;
  } else if (i < 320*128 + 640*128) {
    int ii = i - 320*128;
    int m = ii >> 7, c = ii & 127;                  // K=2: m = e*2 + j
    int e = m >> 1, j = m & 1;
    ws[WT2 + ii] = (e < kE) ? w2[(c*kE + e)*2 + j] : 0.f;
  } else if (i < 320*128 + 640*128 + 960*128) {
    int ii = i - 320*128 - 640*128;
    int m = ii >> 7, c = ii & 127;                  // K=3: m = e*3 + j
    int e = m / 3, j = m - e*3;
    ws[WT3 + ii] = (e < kE) ? w3[(c*kE + e)*3 + j] : 0.f;
  }
  if (i < 128) {
    ws[BIAS3 + i]       = b1[i];
    ws[BIAS3 + 128 + i] = b2[i];
    ws[BIAS3 + 256 + i] = b3[i];
  }
}

// ---------------- conv + bias + relu + L2-normalize, store [B][C][L] ----------------
// block: 128 threads = (pd 0..7) x (cd 0..15); tile: 64 positions x 128 channels
template<int K>
__global__ __launch_bounds__(128) void conv_kernel(
    const float* __restrict__ x,    // [B][L][E]
    const float* __restrict__ wt,   // [320*K][C] zero-padded, m = e*K + j
    const float* __restrict__ bias, // [C]
    float* __restrict__ outT,       // [B][C][L]
    int L)
{
  const int b  = blockIdx.y;
  const int p0 = blockIdx.x * 64;
  const int t  = threadIdx.x;
  const int pd = t >> 4;
  const int cd = t & 15;
  __shared__ float Xt[32][72];      // [e within chunk][position slot], zero-padded

  float acc[8][8];
  #pragma unroll
  for (int a = 0; a < 8; ++a)
    #pragma unroll
    for (int c = 0; c < 8; ++c) acc[a][c] = 0.f;

  for (int ec = 0; ec < 10; ++ec) {           // 10 chunks of 32 e (300 padded to 320)
    __syncthreads();
    #pragma unroll
    for (int i = 0; i < 18; ++i) {            // 32*72 = 2304 slots
      int idx = t + i*128;
      int el = idx & 31, r = idx >> 5;
      int e = ec*32 + el;
      int gp = p0 + r;
      float v = 0.f;
      if (e < kE && r < 64 + K - 1 && gp < L)
        v = x[((size_t)b*L + gp)*kE + e];
      Xt[el][r] = v;
    }
    __syncthreads();
    for (int el = 0; el < 32; ++el) {
      float4 a0 = *(const float4*)&Xt[el][pd*4];
      float4 a1 = *(const float4*)&Xt[el][pd*4 + 4];
      float4 c0 = *(const float4*)&Xt[el][32 + pd*4];
      float4 c1 = *(const float4*)&Xt[el][32 + pd*4 + 4];
      float xa[8] = {a0.x,a0.y,a0.z,a0.w,a1.x,a1.y,a1.z,a1.w};
      float xb[8] = {c0.x,c0.y,c0.z,c0.w,c1.x,c1.y,c1.z,c1.w};
      const int m0 = (ec*32 + el)*K;
      #pragma unroll
      for (int j = 0; j < K; ++j) {
        const float* wrow = wt + (size_t)(m0 + j)*kC;
        float4 w0 = *(const float4*)(wrow + cd*4);
        float4 w1v = *(const float4*)(wrow + 64 + cd*4);
        float wr[8] = {w0.x,w0.y,w0.z,w0.w,w1v.x,w1v.y,w1v.z,w1v.w};
        #pragma unroll
        for (int ip = 0; ip < 8; ++ip) {
          float xv = (ip < 4) ? xa[ip + j] : xb[ip - 4 + j];
          #pragma unroll
          for (int ic = 0; ic < 8; ++ic)
            acc[ip][ic] += xv * wr[ic];
        }
      }
    }
  }
  // bias + relu + per-position L2 norm (sum over 128 channels = 16 cd lanes x 8 ic)
  float s[8];
  #pragma unroll
  for (int ip = 0; ip < 8; ++ip) s[ip] = 0.f;
  #pragma unroll
  for (int ic = 0; ic < 8; ++ic) {
    int c = (ic < 4) ? (cd*4 + ic) : (64 + cd*4 + ic - 4);
    float bv = bias[c];
    #pragma unroll
    for (int ip = 0; ip < 8; ++ip) {
      float y = fmaxf(acc[ip][ic] + bv, 0.f);
      acc[ip][ic] = y;
      s[ip] += y*y;
    }
  }
  #pragma unroll
  for (int off = 1; off < 16; off <<= 1)
    #pragma unroll
    for (int ip = 0; ip < 8; ++ip)
      s[ip] += __shfl_xor(s[ip], off);
  float inv[8];
  #pragma unroll
  for (int ip = 0; ip < 8; ++ip) inv[ip] = 1.f / (sqrtf(s[ip]) + 1e-13f);
  #pragma unroll
  for (int ic = 0; ic < 8; ++ic) {
    int c = (ic < 4) ? (cd*4 + ic) : (64 + cd*4 + ic - 4);
    float* dst = outT + ((size_t)b*kC + c)*L + p0;
    float4 g;
    g.x = acc[0][ic]*inv[0]; g.y = acc[1][ic]*inv[1];
    g.z = acc[2][ic]*inv[2]; g.w = acc[3][ic]*inv[3];
    if (p0 + pd*4 + 3 < L) *(float4*)(dst + pd*4) = g;
    float4 h;
    h.x = acc[4][ic]*inv[4]; h.y = acc[5][ic]*inv[5];
    h.z = acc[6][ic]*inv[6]; h.w = acc[7][ic]*inv[7];
    if (p0 + 32 + pd*4 + 3 < L) *(float4*)(dst + 32 + pd*4) = h;
  }
}

// ---------------- cosine GEMM + RBF kernel pooling ----------------
// block: 256 threads = (tq 0..3) x (td 0..63); covers 32 q x 512 d for one (pair, b)
__global__ __launch_bounds__(256) void pool_kernel(
    const float* __restrict__ qn,    // [3][B][C][Q]
    const float* __restrict__ dn,    // [3][B][C][D]
    const float* __restrict__ qmask, // [B][Q]
    const float* __restrict__ dmask, // [B][D]
    float* __restrict__ pkq)         // [9][B][Q][11]
{
  const float MU[11] = {1.0f,0.9f,0.7f,0.5f,0.3f,0.1f,-0.1f,-0.3f,-0.5f,-0.7f,-0.9f};
  const float NG[11] = {-500000.f,-50.f,-50.f,-50.f,-50.f,-50.f,-50.f,-50.f,-50.f,-50.f,-50.f};
  const int pair = blockIdx.x;
  const int b = blockIdx.y;
  const int qi = pair / 3, dj = pair - qi*3;
  const float* qb = qn + (size_t)(qi*kB + b) * kC * kQ;
  const float* db = dn + (size_t)(dj*kB + b) * kC * kD;
  const int t = threadIdx.x;
  const int tq = t >> 6, td = t & 63;
  __shared__ float qT[16][36];
  __shared__ float dT[16][516];

  float acc[8][8];
  #pragma unroll
  for (int a = 0; a < 8; ++a)
    #pragma unroll
    for (int c = 0; c < 8; ++c) acc[a][c] = 0.f;

  for (int cc = 0; cc < 8; ++cc) {      // 8 chunks of 16 channels
    __syncthreads();
    if (t < 128) {
      int q4 = (t & 7)*4, cl = t >> 3;
      *(float4*)&qT[cl][q4] = *(const float4*)(qb + (size_t)(cc*16 + cl)*kQ + q4);
    }
    #pragma unroll
    for (int i = 0; i < 8; ++i) {
      int f = t + i*256;
      int d4 = (f & 127)*4, cl = f >> 7;
      *(float4*)&dT[cl][d4] = *(const float4*)(db + (size_t)(cc*16 + cl)*kD + d4);
    }
    __syncthreads();
    for (int c = 0; c < 16; ++c) {
      float4 q0 = *(const float4*)&qT[c][tq*4];
      float4 q1 = *(const float4*)&qT[c][16 + tq*4];
      float4 d0 = *(const float4*)&dT[c][td*4];
      float4 d1 = *(const float4*)&dT[c][256 + td*4];
      float qa[8] = {q0.x,q0.y,q0.z,q0.w,q1.x,q1.y,q1.z,q1.w};
      float da[8] = {d0.x,d0.y,d0.z,d0.w,d1.x,d1.y,d1.z,d1.w};
      #pragma unroll
      for (int i2 = 0; i2 < 8; ++i2)
        #pragma unroll
        for (int j2 = 0; j2 < 8; ++j2)
          acc[i2][j2] += qa[i2]*da[j2];
    }
  }
  // masks
  float qmv[8], dmv[8];
  #pragma unroll
  for (int i2 = 0; i2 < 8; ++i2) {
    int q = (i2 < 4) ? (tq*4 + i2) : (16 + tq*4 + i2 - 4);
    qmv[i2] = qmask[b*kQ + q];
  }
  #pragma unroll
  for (int j2 = 0; j2 < 8; ++j2) {
    int d = (j2 < 4) ? (td*4 + j2) : (256 + td*4 + j2 - 4);
    dmv[j2] = dmask[b*kD + d];
  }
  // RBF kernels; pkq[q][k] = qm_q * sum_d dm_d * exp(-(cos*m - mu)^2/(2 s^2))
  float pk[8][11];
  #pragma unroll
  for (int i2 = 0; i2 < 8; ++i2)
    #pragma unroll
    for (int k = 0; k < 11; ++k) pk[i2][k] = 0.f;
  #pragma unroll
  for (int i2 = 0; i2 < 8; ++i2) {
    #pragma unroll
    for (int j2 = 0; j2 < 8; ++j2) {
      float sv = acc[i2][j2] * qmv[i2] * dmv[j2];   // masked cosine
      #pragma unroll
      for (int k = 0; k < 11; ++k) {
        float dd = sv - MU[k];
        float a = dd*dd*NG[k];
        pk[i2][k] += dmv[j2] * __expf(a);
      }
    }
  }
  // butterfly sum over the 64 lanes (td covers all 512 d)
  #pragma unroll
  for (int off = 1; off < 64; off <<= 1)
    #pragma unroll
    for (int i2 = 0; i2 < 8; ++i2)
      #pragma unroll
      for (int k = 0; k < 11; ++k)
        pk[i2][k] += __shfl_xor(pk[i2][k], off);
  // store: lane l<44 handles (i2=l/11, k=l%11) for both q groups
  float vA = 0.f, vB = 0.f;
  #pragma unroll
  for (int i2 = 0; i2 < 4; ++i2)
    #pragma unroll
    for (int k = 0; k < 11; ++k) {
      vA = (td == i2*11 + k) ? pk[i2][k]   : vA;
      vB = (td == i2*11 + k) ? pk[i2+4][k] : vB;
    }
  if (td < 44) {
    int i2 = td / 11, k = td - i2*11;
    int qA = tq*4 + i2, qB = 16 + tq*4 + i2;
    pkq[(((size_t)pair*kB + b)*kQ + qA)*kK + k] = vA * qmask[b*kQ + qA];
    pkq[(((size_t)pair*kB + b)*kQ + qB)*kK + k] = vB * qmask[b*kQ + qB];
  }
}

// ---------------- log-pool + dense layers ----------------
__global__ __launch_bounds__(128) void finalize_kernel(
    const float* __restrict__ pkq, const float* __restrict__ qmask,
    const float* __restrict__ dmask, const float* __restrict__ nsp,
    const float* __restrict__ dw, const float* __restrict__ dbp,
    const float* __restrict__ dmw, const float* __restrict__ dmbp,
    const float* __restrict__ dcw, float* __restrict__ out)
{
  const int b = blockIdx.x;
  const int t = threadIdx.x;
  __shared__ float sh[4];
  float dl = 0.f;
  for (int d = t; d < kD; d += 128) dl += dmask[b*kD + d];
  #pragma unroll
  for (int off = 1; off < 64; off <<= 1) dl += __shfl_xor(dl, off);
  if ((t & 63) == 0) sh[t >> 6] = dl;
  __syncthreads();
  const float idl = 1.f / (sh[0] + sh[1]);
  const float sc = nsp[0];
  float ps = 0.f, pm = 0.f;
  for (int i = t; i < 99; i += 128) {
    int pr = i / 11, kk = i - pr*11;
    const float* base = pkq + ((size_t)pr*kB + b)*kQ*kK + kk;
    float ss = 0.f, sm = 0.f;
    for (int q = 0; q < kQ; ++q) {
      float v = base[q*kK];
      float qq = qmask[b*kQ + q];
      ss += __logf(fmaxf(v, 1e-10f)) * qq;
      sm += __logf(fmaxf(v*idl, 1e-10f)) * qq;
    }
    ps += dw[i] * ss;
    pm += dmw[i] * sm;
  }
  ps *= sc; pm *= sc;
  #pragma unroll
  for (int off = 1; off < 64; off <<= 1) { ps += __shfl_xor(ps, off); pm += __shfl_xor(pm, off); }
  __syncthreads();
  if ((t & 63) == 0) { sh[t >> 6] = ps; sh[2 + (t >> 6)] = pm; }
  __syncthreads();
  if (t == 0) {
    float PS = sh[0] + sh[1] + dbp[0];
    float PM = sh[2] + sh[3] + dmbp[0];
    out[b] = dcw[0]*PS + dcw[1]*PM;
  }
}

} // namespace

extern "C" void kernel_launch(void* const* d_in, const int* in_sizes, int n_in,
                              void* d_out, int out_size, void* d_ws, size_t ws_size,
                              hipStream_t stream) {
  const float* qe  = (const float*)d_in[0];
  const float* de  = (const float*)d_in[1];
  const float* qm  = (const float*)d_in[2];
  const float* dm  = (const float*)d_in[3];
  const float* w1  = (const float*)d_in[4];
  const float* b1  = (const float*)d_in[5];
  const float* w2  = (const float*)d_in[6];
  const float* b2  = (const float*)d_in[7];
  const float* w3  = (const float*)d_in[8];
  const float* b3  = (const float*)d_in[9];
  const float* ns  = (const float*)d_in[10];
  const float* dw  = (const float*)d_in[11];
  const float* db  = (const float*)d_in[12];
  const float* dmw = (const float*)d_in[13];
  const float* dmb = (const float*)d_in[14];
  const float* dcw = (const float*)d_in[15];
  float* out = (float*)d_out;
  float* ws  = (float*)d_ws;

  prep_kernel<<<960, 256, 0, stream>>>(w1, w2, w3, b1, b2, b3, ws);

  // q convs (L=32, one 64-wide tile)
  conv_kernel<1><<<dim3(1,kB), 128, 0, stream>>>(qe, ws + WT1, ws + BIAS3,       ws + QN,                         kQ);
  conv_kernel<2><<<dim3(1,kB), 128, 0, stream>>>(qe, ws + WT2, ws + BIAS3 + 128, ws + QN + (size_t)1*kB*kC*kQ,    kQ);
  conv_kernel<3><<<dim3(1,kB), 128, 0, stream>>>(qe, ws + WT3, ws + BIAS3 + 256, ws + QN + (size_t)2*kB*kC*kQ,    kQ);
  // d convs (L=512, 8 tiles)
  conv_kernel<1><<<dim3(8,kB), 128, 0, stream>>>(de, ws + WT1, ws + BIAS3,       ws + DN,                         kD);
  conv_kernel<2><<<dim3(8,kB), 128, 0, stream>>>(de, ws + WT2, ws + BIAS3 + 128, ws + DN + (size_t)1*kB*kC*kD,    kD);
  conv_kernel<3><<<dim3(8,kB), 128, 0, stream>>>(de, ws + WT3, ws + BIAS3 + 256, ws + DN + (size_t)2*kB*kC*kD,    kD);

  pool_kernel<<<dim3(9,kB), 256, 0, stream>>>(ws + QN, ws + DN, qm, dm, ws + PKQ);

  finalize_kernel<<<kB, 128, 0, stream>>>(ws + PKQ, qm, dm, ns, dw, db, dmw, dmb, dcw, out);
}

// Round 2
// 399.362 us; speedup vs baseline: 2.6421x; 2.6421x over previous
//
#include <hip/hip_runtime.h>
#include <hip/hip_bf16.h>
#include <cstdint>

namespace {

typedef __bf16 bf8v __attribute__((ext_vector_type(8)));
typedef float  f4v  __attribute__((ext_vector_type(4)));

constexpr int kB = 128;   // batch
constexpr int kQ = 32;    // query len
constexpr int kD = 512;   // doc len
constexpr int kE = 300;   // embed dim
constexpr int kC = 128;   // conv channels
constexpr int kK = 11;    // RBF kernels

// workspace layout
// bf16 region at start: packed weights [6 j-slabs][128][320] = 245760 bf16 = 122880 f32
constexpr size_t WB2_OFF = 40960;    // bf16 units: conv2 (j=0,1)
constexpr size_t WB3_OFF = 122880;   // bf16 units: conv3 (j=0,1,2)
// f32 offsets
constexpr size_t QN  = 122880;       // [3][B][C][Q] normalized q conv outputs
constexpr size_t DN  = 1695744;      // [3][B][C][D]
constexpr size_t PKQ = 26861568;     // [9][B][Q][11]
// total 27267072 floats = 109.07 MB

// ---------------- weight transpose/pad to bf16 [j][c][320] ----------------
__global__ __launch_bounds__(256) void prep_kernel(
    const float* __restrict__ w1, const float* __restrict__ w2, const float* __restrict__ w3,
    __bf16* __restrict__ wb)
{
  int i = blockIdx.x * 256 + threadIdx.x;   // 0..245759
  if (i < 40960) {
    int c = i / 320, e = i - c * 320;
    float v = (e < kE) ? w1[c * kE + e] : 0.f;
    wb[i] = (__bf16)v;
  } else if (i < 122880) {
    int i2 = i - 40960;
    int j = i2 / 40960, r = i2 - j * 40960;
    int c = r / 320, e = r - c * 320;
    float v = (e < kE) ? w2[(c * kE + e) * 2 + j] : 0.f;
    wb[i] = (__bf16)v;
  } else if (i < 245760) {
    int i3 = i - 122880;
    int j = i3 / 40960, r = i3 - j * 40960;
    int c = r / 320, e = r - c * 320;
    float v = (e < kE) ? w3[(c * kE + e) * 3 + j] : 0.f;
    wb[i] = (__bf16)v;
  }
}

// ---------------- MFMA conv + bias + relu + L2-normalize, store [B][C][L] ----------------
// 256 threads = 4 waves. Tile: 64 positions x 128 channels.
// Wave (wm, wn): rows [p0+wm*32, +32), cols [wn*64, +64); frags 2 m x 4 n of 16x16.
// A: x[p+j, e] loaded f32 from global, cvt to bf16 in-reg. B: packed bf16 weights.
template<int KF>
__global__ __launch_bounds__(256) void conv_mfma(
    const float* __restrict__ x,      // [B][L][300] f32
    const __bf16* __restrict__ wb,    // [KF][128][320] bf16
    const float* __restrict__ bias,   // [128]
    float* __restrict__ outT,         // [B][128][L] f32
    int L)
{
  const int b  = blockIdx.y;
  const int p0 = blockIdx.x * 64;
  const int t  = threadIdx.x;
  const int w  = t >> 6, l = t & 63;
  const int wm = w & 1, wn = w >> 1;
  const int lr = l & 15, g = l >> 4;
  __shared__ float sqs[2][64];

  f4v acc[2][4];
  #pragma unroll
  for (int mf = 0; mf < 2; ++mf)
    #pragma unroll
    for (int nf = 0; nf < 4; ++nf)
      acc[mf][nf] = (f4v)0.f;

  const float* xb = x + (size_t)b * L * kE;
  const int e0g = g * 8;

  for (int ks = 0; ks < 10; ++ks) {
    const int kbase = ks * 32;
    const int e0 = kbase + e0g;           // multiple of 8, <= 312
    #pragma unroll
    for (int j = 0; j < KF; ++j) {
      bf8v A[2];
      #pragma unroll
      for (int mf = 0; mf < 2; ++mf) {
        const int row = p0 + wm * 32 + mf * 16 + lr + j;
        float xf[8];
        #pragma unroll
        for (int q = 0; q < 8; ++q) xf[q] = 0.f;
        if (row < L) {
          const float* src = xb + (size_t)row * kE + e0;
          if (e0 + 8 <= kE) {
            float4 v0 = *(const float4*)src;
            float4 v1 = *(const float4*)(src + 4);
            xf[0] = v0.x; xf[1] = v0.y; xf[2] = v0.z; xf[3] = v0.w;
            xf[4] = v1.x; xf[5] = v1.y; xf[6] = v1.z; xf[7] = v1.w;
          } else if (e0 < kE) {           // e0 == 296: 4 valid + 4 zero
            float4 v0 = *(const float4*)src;
            xf[0] = v0.x; xf[1] = v0.y; xf[2] = v0.z; xf[3] = v0.w;
          }
        }
        bf8v a;
        #pragma unroll
        for (int q = 0; q < 8; ++q) a[q] = (__bf16)xf[q];
        A[mf] = a;
      }
      #pragma unroll
      for (int nf = 0; nf < 4; ++nf) {
        const int c = wn * 64 + nf * 16 + lr;
        bf8v bfr = *(const bf8v*)(wb + ((size_t)(j * kC + c)) * 320 + kbase + e0g);
        #pragma unroll
        for (int mf = 0; mf < 2; ++mf)
          acc[mf][nf] = __builtin_amdgcn_mfma_f32_16x16x32_bf16(A[mf], bfr, acc[mf][nf], 0, 0, 0);
      }
    }
  }

  // bias + relu + per-position sum of squares
  float bvs[4];
  #pragma unroll
  for (int nf = 0; nf < 4; ++nf) bvs[nf] = bias[wn * 64 + nf * 16 + lr];

  f4v ssum[2];
  #pragma unroll
  for (int mf = 0; mf < 2; ++mf) {
    ssum[mf] = (f4v)0.f;
    #pragma unroll
    for (int nf = 0; nf < 4; ++nf)
      #pragma unroll
      for (int r = 0; r < 4; ++r) {
        float y = fmaxf(acc[mf][nf][r] + bvs[nf], 0.f);
        acc[mf][nf][r] = y;
        ssum[mf][r] += y * y;
      }
  }
  // reduce over the 16 col-lanes (cols this wave owns)
  #pragma unroll
  for (int off = 1; off < 16; off <<= 1)
    #pragma unroll
    for (int mf = 0; mf < 2; ++mf)
      #pragma unroll
      for (int r = 0; r < 4; ++r)
        ssum[mf][r] += __shfl_xor(ssum[mf][r], off);

  // exchange with the other wn-half (other 64 cols) via LDS
  if (lr == 0) {
    #pragma unroll
    for (int mf = 0; mf < 2; ++mf)
      *(float4*)&sqs[wn][wm * 32 + mf * 16 + g * 4] = *(float4*)&ssum[mf];
  }
  __syncthreads();
  f4v inv[2];
  #pragma unroll
  for (int mf = 0; mf < 2; ++mf) {
    float4 o = *(const float4*)&sqs[1 - wn][wm * 32 + mf * 16 + g * 4];
    inv[mf][0] = 1.f / (sqrtf(ssum[mf][0] + o.x) + 1e-13f);
    inv[mf][1] = 1.f / (sqrtf(ssum[mf][1] + o.y) + 1e-13f);
    inv[mf][2] = 1.f / (sqrtf(ssum[mf][2] + o.z) + 1e-13f);
    inv[mf][3] = 1.f / (sqrtf(ssum[mf][3] + o.w) + 1e-13f);
  }
  #pragma unroll
  for (int mf = 0; mf < 2; ++mf) {
    const int p = p0 + wm * 32 + mf * 16 + g * 4;
    if (p < L) {
      #pragma unroll
      for (int nf = 0; nf < 4; ++nf) {
        const int c = wn * 64 + nf * 16 + lr;
        float4 vo;
        vo.x = acc[mf][nf][0] * inv[mf][0];
        vo.y = acc[mf][nf][1] * inv[mf][1];
        vo.z = acc[mf][nf][2] * inv[mf][2];
        vo.w = acc[mf][nf][3] * inv[mf][3];
        *(float4*)(outT + ((size_t)b * kC + c) * L + p) = vo;
      }
    }
  }
}

// ---------------- cosine GEMM + RBF kernel pooling (unchanged) ----------------
__global__ __launch_bounds__(256) void pool_kernel(
    const float* __restrict__ qn,    // [3][B][C][Q]
    const float* __restrict__ dn,    // [3][B][C][D]
    const float* __restrict__ qmask, // [B][Q]
    const float* __restrict__ dmask, // [B][D]
    float* __restrict__ pkq)         // [9][B][Q][11]
{
  const float MU[11] = {1.0f,0.9f,0.7f,0.5f,0.3f,0.1f,-0.1f,-0.3f,-0.5f,-0.7f,-0.9f};
  const float NG[11] = {-500000.f,-50.f,-50.f,-50.f,-50.f,-50.f,-50.f,-50.f,-50.f,-50.f,-50.f};
  const int pair = blockIdx.x;
  const int b = blockIdx.y;
  const int qi = pair / 3, dj = pair - qi*3;
  const float* qb = qn + (size_t)(qi*kB + b) * kC * kQ;
  const float* db = dn + (size_t)(dj*kB + b) * kC * kD;
  const int t = threadIdx.x;
  const int tq = t >> 6, td = t & 63;
  __shared__ float qT[16][36];
  __shared__ float dT[16][516];

  float acc[8][8];
  #pragma unroll
  for (int a = 0; a < 8; ++a)
    #pragma unroll
    for (int c = 0; c < 8; ++c) acc[a][c] = 0.f;

  for (int cc = 0; cc < 8; ++cc) {      // 8 chunks of 16 channels
    __syncthreads();
    if (t < 128) {
      int q4 = (t & 7)*4, cl = t >> 3;
      *(float4*)&qT[cl][q4] = *(const float4*)(qb + (size_t)(cc*16 + cl)*kQ + q4);
    }
    #pragma unroll
    for (int i = 0; i < 8; ++i) {
      int f = t + i*256;
      int d4 = (f & 127)*4, cl = f >> 7;
      *(float4*)&dT[cl][d4] = *(const float4*)(db + (size_t)(cc*16 + cl)*kD + d4);
    }
    __syncthreads();
    for (int c = 0; c < 16; ++c) {
      float4 q0 = *(const float4*)&qT[c][tq*4];
      float4 q1 = *(const float4*)&qT[c][16 + tq*4];
      float4 d0 = *(const float4*)&dT[c][td*4];
      float4 d1 = *(const float4*)&dT[c][256 + td*4];
      float qa[8] = {q0.x,q0.y,q0.z,q0.w,q1.x,q1.y,q1.z,q1.w};
      float da[8] = {d0.x,d0.y,d0.z,d0.w,d1.x,d1.y,d1.z,d1.w};
      #pragma unroll
      for (int i2 = 0; i2 < 8; ++i2)
        #pragma unroll
        for (int j2 = 0; j2 < 8; ++j2)
          acc[i2][j2] += qa[i2]*da[j2];
    }
  }
  float qmv[8], dmv[8];
  #pragma unroll
  for (int i2 = 0; i2 < 8; ++i2) {
    int q = (i2 < 4) ? (tq*4 + i2) : (16 + tq*4 + i2 - 4);
    qmv[i2] = qmask[b*kQ + q];
  }
  #pragma unroll
  for (int j2 = 0; j2 < 8; ++j2) {
    int d = (j2 < 4) ? (td*4 + j2) : (256 + td*4 + j2 - 4);
    dmv[j2] = dmask[b*kD + d];
  }
  float pk[8][11];
  #pragma unroll
  for (int i2 = 0; i2 < 8; ++i2)
    #pragma unroll
    for (int k = 0; k < 11; ++k) pk[i2][k] = 0.f;
  #pragma unroll
  for (int i2 = 0; i2 < 8; ++i2) {
    #pragma unroll
    for (int j2 = 0; j2 < 8; ++j2) {
      float sv = acc[i2][j2] * qmv[i2] * dmv[j2];
      #pragma unroll
      for (int k = 0; k < 11; ++k) {
        float dd = sv - MU[k];
        float a = dd*dd*NG[k];
        pk[i2][k] += dmv[j2] * __expf(a);
      }
    }
  }
  #pragma unroll
  for (int off = 1; off < 64; off <<= 1)
    #pragma unroll
    for (int i2 = 0; i2 < 8; ++i2)
      #pragma unroll
      for (int k = 0; k < 11; ++k)
        pk[i2][k] += __shfl_xor(pk[i2][k], off);
  float vA = 0.f, vB = 0.f;
  #pragma unroll
  for (int i2 = 0; i2 < 4; ++i2)
    #pragma unroll
    for (int k = 0; k < 11; ++k) {
      vA = (td == i2*11 + k) ? pk[i2][k]   : vA;
      vB = (td == i2*11 + k) ? pk[i2+4][k] : vB;
    }
  if (td < 44) {
    int i2 = td / 11, k = td - i2*11;
    int qA = tq*4 + i2, qB = 16 + tq*4 + i2;
    pkq[(((size_t)pair*kB + b)*kQ + qA)*kK + k] = vA * qmask[b*kQ + qA];
    pkq[(((size_t)pair*kB + b)*kQ + qB)*kK + k] = vB * qmask[b*kQ + qB];
  }
}

// ---------------- log-pool + dense layers (unchanged) ----------------
__global__ __launch_bounds__(128) void finalize_kernel(
    const float* __restrict__ pkq, const float* __restrict__ qmask,
    const float* __restrict__ dmask, const float* __restrict__ nsp,
    const float* __restrict__ dw, const float* __restrict__ dbp,
    const float* __restrict__ dmw, const float* __restrict__ dmbp,
    const float* __restrict__ dcw, float* __restrict__ out)
{
  const int b = blockIdx.x;
  const int t = threadIdx.x;
  __shared__ float sh[4];
  float dl = 0.f;
  for (int d = t; d < kD; d += 128) dl += dmask[b*kD + d];
  #pragma unroll
  for (int off = 1; off < 64; off <<= 1) dl += __shfl_xor(dl, off);
  if ((t & 63) == 0) sh[t >> 6] = dl;
  __syncthreads();
  const float idl = 1.f / (sh[0] + sh[1]);
  const float sc = nsp[0];
  float ps = 0.f, pm = 0.f;
  for (int i = t; i < 99; i += 128) {
    int pr = i / 11, kk = i - pr*11;
    const float* base = pkq + ((size_t)pr*kB + b)*kQ*kK + kk;
    float ss = 0.f, sm = 0.f;
    for (int q = 0; q < kQ; ++q) {
      float v = base[q*kK];
      float qq = qmask[b*kQ + q];
      ss += __logf(fmaxf(v, 1e-10f)) * qq;
      sm += __logf(fmaxf(v*idl, 1e-10f)) * qq;
    }
    ps += dw[i] * ss;
    pm += dmw[i] * sm;
  }
  ps *= sc; pm *= sc;
  #pragma unroll
  for (int off = 1; off < 64; off <<= 1) { ps += __shfl_xor(ps, off); pm += __shfl_xor(pm, off); }
  __syncthreads();
  if ((t & 63) == 0) { sh[t >> 6] = ps; sh[2 + (t >> 6)] = pm; }
  __syncthreads();
  if (t == 0) {
    float PS = sh[0] + sh[1] + dbp[0];
    float PM = sh[2] + sh[3] + dmbp[0];
    out[b] = dcw[0]*PS + dcw[1]*PM;
  }
}

} // namespace

extern "C" void kernel_launch(void* const* d_in, const int* in_sizes, int n_in,
                              void* d_out, int out_size, void* d_ws, size_t ws_size,
                              hipStream_t stream) {
  const float* qe  = (const float*)d_in[0];
  const float* de  = (const float*)d_in[1];
  const float* qm  = (const float*)d_in[2];
  const float* dm  = (const float*)d_in[3];
  const float* w1  = (const float*)d_in[4];
  const float* b1  = (const float*)d_in[5];
  const float* w2  = (const float*)d_in[6];
  const float* b2  = (const float*)d_in[7];
  const float* w3  = (const float*)d_in[8];
  const float* b3  = (const float*)d_in[9];
  const float* ns  = (const float*)d_in[10];
  const float* dw  = (const float*)d_in[11];
  const float* db  = (const float*)d_in[12];
  const float* dmw = (const float*)d_in[13];
  const float* dmb = (const float*)d_in[14];
  const float* dcw = (const float*)d_in[15];
  float* out = (float*)d_out;
  float* ws  = (float*)d_ws;
  __bf16* wb = (__bf16*)d_ws;

  float* qn  = ws + QN;
  float* dn  = ws + DN;
  float* pkq = ws + PKQ;

  prep_kernel<<<960, 256, 0, stream>>>(w1, w2, w3, wb);

  // q convs (L=32)
  conv_mfma<1><<<dim3(1,kB), 256, 0, stream>>>(qe, wb,           b1, qn,                        kQ);
  conv_mfma<2><<<dim3(1,kB), 256, 0, stream>>>(qe, wb + WB2_OFF, b2, qn + (size_t)1*kB*kC*kQ,   kQ);
  conv_mfma<3><<<dim3(1,kB), 256, 0, stream>>>(qe, wb + WB3_OFF, b3, qn + (size_t)2*kB*kC*kQ,   kQ);
  // d convs (L=512)
  conv_mfma<1><<<dim3(8,kB), 256, 0, stream>>>(de, wb,           b1, dn,                        kD);
  conv_mfma<2><<<dim3(8,kB), 256, 0, stream>>>(de, wb + WB2_OFF, b2, dn + (size_t)1*kB*kC*kD,   kD);
  conv_mfma<3><<<dim3(8,kB), 256, 0, stream>>>(de, wb + WB3_OFF, b3, dn + (size_t)2*kB*kC*kD,   kD);

  pool_kernel<<<dim3(9,kB), 256, 0, stream>>>(qn, dn, qm, dm, pkq);

  finalize_kernel<<<kB, 128, 0, stream>>>(pkq, qm, dm, ns, dw, db, dmw, dmb, dcw, out);
}

// Round 3
// 263.843 us; speedup vs baseline: 3.9992x; 1.5136x over previous
//
#include <hip/hip_runtime.h>
#include <hip/hip_bf16.h>
#include <cstdint>

namespace {

typedef __bf16 bf8v __attribute__((ext_vector_type(8)));
typedef __bf16 bf4v __attribute__((ext_vector_type(4)));
typedef float  f4v  __attribute__((ext_vector_type(4)));

constexpr int kB = 128;   // batch
constexpr int kQ = 32;    // query len
constexpr int kD = 512;   // doc len
constexpr int kE = 300;   // embed dim
constexpr int kC = 128;   // conv channels
constexpr int kK = 11;    // RBF kernels

// workspace layout (bytes)
// wb:  [6 j-slabs][128][320] bf16 = 491520 B   (slabs: c1 j0 | c2 j0 j1 | c3 j0 j1 j2)
// qnb: [3][B][32][128]  bf16 = 3.1 MB  (position-major, normalized)
// dnb: [3][B][512][128] bf16 = 50.3 MB
// pkq: [9][B][32][11]   f32  = 1.6 MB
constexpr size_t QNB_B = 491520;
constexpr size_t DNB_B = 3637248;
constexpr size_t PKQ_B = 53968896;

constexpr float LOG2E = 1.4426950408889634f;

// ---------------- weight transpose/pad to bf16 [j][c][320] ----------------
__global__ __launch_bounds__(256) void prep_kernel(
    const float* __restrict__ w1, const float* __restrict__ w2, const float* __restrict__ w3,
    __bf16* __restrict__ wb)
{
  int i = blockIdx.x * 256 + threadIdx.x;   // 0..245759
  if (i < 40960) {
    int c = i / 320, e = i - c * 320;
    float v = (e < kE) ? w1[c * kE + e] : 0.f;
    wb[i] = (__bf16)v;
  } else if (i < 122880) {
    int i2 = i - 40960;
    int j = i2 / 40960, r = i2 - j * 40960;
    int c = r / 320, e = r - c * 320;
    float v = (e < kE) ? w2[(c * kE + e) * 2 + j] : 0.f;
    wb[i] = (__bf16)v;
  } else if (i < 245760) {
    int i3 = i - 122880;
    int j = i3 / 40960, r = i3 - j * 40960;
    int c = r / 320, e = r - c * 320;
    float v = (e < kE) ? w3[(c * kE + e) * 3 + j] : 0.f;
    wb[i] = (__bf16)v;
  }
}

// ---------------- fused conv (all 3 widths) + bias + relu + L2-norm -> bf16 [L][C] ----------------
// grid (9, B): x==0 -> query (L=32), x=1..8 -> doc tile (p0=(x-1)*64, L=512)
// 256 threads = 4 waves; tile 64 pos x 128 ch; wave (wm,wn) -> rows wm*32+, cols wn*64+
__global__ __launch_bounds__(256) void conv_fused(
    const float* __restrict__ qe, const float* __restrict__ de,
    const __bf16* __restrict__ wb,
    const float* __restrict__ b1, const float* __restrict__ b2, const float* __restrict__ b3,
    __bf16* __restrict__ qnb, __bf16* __restrict__ dnb)
{
  const int bx = blockIdx.x;
  const int b  = blockIdx.y;
  const bool isq = (bx == 0);
  const int L  = isq ? kQ : kD;
  const int p0 = isq ? 0 : (bx - 1) * 64;
  const float* xsrc = (isq ? qe : de) + (size_t)b * L * kE;

  const int t = threadIdx.x;
  const int w = t >> 6, l = t & 63;
  const int wm = w & 1, wn = w >> 1;
  const int lr = l & 15, g = l >> 4;

  __shared__ __align__(16) __bf16 Xs[66 * 328];   // [row][e], e padded to 328
  __shared__ float sqs[2][64];

  // stage x rows p0..p0+65, e 0..327 (zero-pad) as bf16
  for (int idx = t; idx < 66 * 82; idx += 256) {
    int row = idx / 82, c4 = idx - row * 82;
    int gp = p0 + row;
    float4 v = make_float4(0.f, 0.f, 0.f, 0.f);
    if (gp < L && c4 < 75) v = *(const float4*)(xsrc + (size_t)gp * kE + c4 * 4);
    bf4v hv = { (__bf16)v.x, (__bf16)v.y, (__bf16)v.z, (__bf16)v.w };
    *(bf4v*)&Xs[row * 328 + c4 * 4] = hv;
  }
  __syncthreads();

  const size_t wbase[3] = {0, 40960, 122880};

  #pragma unroll
  for (int c0 = 0; c0 < 3; ++c0) {
    const int KF = c0 + 1;
    f4v acc[2][4];
    #pragma unroll
    for (int mf = 0; mf < 2; ++mf)
      #pragma unroll
      for (int nf = 0; nf < 4; ++nf)
        acc[mf][nf] = (f4v)0.f;

    for (int ks = 0; ks < 10; ++ks) {
      #pragma unroll
      for (int j = 0; j < KF; ++j) {
        bf8v A[2];
        #pragma unroll
        for (int mf = 0; mf < 2; ++mf) {
          int row = wm * 32 + mf * 16 + lr + j;
          A[mf] = *(const bf8v*)&Xs[row * 328 + ks * 32 + g * 8];
        }
        const __bf16* wj = wb + wbase[c0] + (size_t)j * 40960 + (size_t)(ks * 32 + g * 8);
        #pragma unroll
        for (int nf = 0; nf < 4; ++nf) {
          int c = wn * 64 + nf * 16 + lr;
          bf8v B = *(const bf8v*)(wj + (size_t)c * 320);
          acc[0][nf] = __builtin_amdgcn_mfma_f32_16x16x32_bf16(A[0], B, acc[0][nf], 0, 0, 0);
          acc[1][nf] = __builtin_amdgcn_mfma_f32_16x16x32_bf16(A[1], B, acc[1][nf], 0, 0, 0);
        }
      }
    }

    // epilogue: bias + relu + L2 norm over 128 channels
    const float* bias = (c0 == 0) ? b1 : ((c0 == 1) ? b2 : b3);
    float bvs[4];
    #pragma unroll
    for (int nf = 0; nf < 4; ++nf) bvs[nf] = bias[wn * 64 + nf * 16 + lr];

    f4v ssum[2];
    #pragma unroll
    for (int mf = 0; mf < 2; ++mf) {
      ssum[mf] = (f4v)0.f;
      #pragma unroll
      for (int nf = 0; nf < 4; ++nf)
        #pragma unroll
        for (int r = 0; r < 4; ++r) {
          float y = fmaxf(acc[mf][nf][r] + bvs[nf], 0.f);
          acc[mf][nf][r] = y;
          ssum[mf][r] += y * y;
        }
    }
    #pragma unroll
    for (int off = 1; off < 16; off <<= 1)
      #pragma unroll
      for (int mf = 0; mf < 2; ++mf)
        #pragma unroll
        for (int r = 0; r < 4; ++r)
          ssum[mf][r] += __shfl_xor(ssum[mf][r], off);

    __syncthreads();              // sqs reuse across c0 iterations
    if (lr == 0) {
      #pragma unroll
      for (int mf = 0; mf < 2; ++mf)
        *(float4*)&sqs[wn][wm * 32 + mf * 16 + g * 4] = *(float4*)&ssum[mf];
    }
    __syncthreads();
    f4v inv[2];
    #pragma unroll
    for (int mf = 0; mf < 2; ++mf) {
      float4 o = *(const float4*)&sqs[1 - wn][wm * 32 + mf * 16 + g * 4];
      inv[mf][0] = 1.f / (sqrtf(ssum[mf][0] + o.x) + 1e-13f);
      inv[mf][1] = 1.f / (sqrtf(ssum[mf][1] + o.y) + 1e-13f);
      inv[mf][2] = 1.f / (sqrtf(ssum[mf][2] + o.z) + 1e-13f);
      inv[mf][3] = 1.f / (sqrtf(ssum[mf][3] + o.w) + 1e-13f);
    }
    // store bf16 [B][L][C]
    __bf16* outp = (isq ? qnb : dnb) + ((size_t)(c0 * kB + b)) * L * kC;
    #pragma unroll
    for (int mf = 0; mf < 2; ++mf) {
      #pragma unroll
      for (int r = 0; r < 4; ++r) {
        int gp = p0 + wm * 32 + mf * 16 + g * 4 + r;
        if (gp < L) {
          #pragma unroll
          for (int nf = 0; nf < 4; ++nf) {
            int c = wn * 64 + nf * 16 + lr;
            outp[(size_t)gp * kC + c] = (__bf16)(acc[mf][nf][r] * inv[mf][r]);
          }
        }
      }
    }
  }
}

// ---------------- MFMA cosine + RBF pooling ----------------
// grid (9, B), 256 threads = 4 waves. Per block: S[512 d][32 q] for one (pair,b).
// M-side = d (A-frags from dnb), N-side = q (B-frags from qnb).
// Wave w owns d-tiles w*8..w*8+7; each lane owns q cols {lr, 16+lr} -> pk[2][11].
__global__ __launch_bounds__(256) void pool_mfma(
    const __bf16* __restrict__ qnb,  // [3][B][32][128]
    const __bf16* __restrict__ dnb,  // [3][B][512][128]
    const float* __restrict__ qmask, // [B][32]
    const float* __restrict__ dmask, // [B][512]
    float* __restrict__ pkq)         // [9][B][32][11]
{
  const int pair = blockIdx.x;
  const int b = blockIdx.y;
  const int qi = pair / 3, dj = pair - qi * 3;
  const __bf16* qb = qnb + ((size_t)qi * kB + b) * kQ * kC;
  const __bf16* db = dnb + ((size_t)dj * kB + b) * kD * kC;

  const int t = threadIdx.x;
  const int w = t >> 6, l = t & 63;
  const int lr = l & 15, g = l >> 4;

  __shared__ float red[4][2][16][kK];

  // q-side B-frags: 2 q-tiles x 4 k-chunks, kept in registers
  bf8v Bq[2][4];
  #pragma unroll
  for (int qt = 0; qt < 2; ++qt)
    #pragma unroll
    for (int kc = 0; kc < 4; ++kc)
      Bq[qt][kc] = *(const bf8v*)&qb[(size_t)(qt * 16 + lr) * kC + kc * 32 + g * 8];

  float qmv[2];
  #pragma unroll
  for (int qt = 0; qt < 2; ++qt) qmv[qt] = qmask[b * kQ + qt * 16 + lr];

  // RBF constants (exp2 domain)
  const float c1[10] = { 129.84255368f, 100.98865286f,  72.13475204f,  43.28085123f,  14.42695041f,
                         -14.42695041f, -43.28085123f, -72.13475204f, -100.98865286f, -129.84255368f };
  const float c2[10] = { -58.42914915f, -35.34602850f, -18.03368801f, -6.49212768f, -0.72134752f,
                          -0.72134752f,  -6.49212768f, -18.03368801f, -35.34602850f, -58.42914915f };
  const float C50 = -50.f * LOG2E;
  const float C0  = -500000.f * LOG2E;

  float pk[2][kK];
  #pragma unroll
  for (int qt = 0; qt < 2; ++qt)
    #pragma unroll
    for (int k = 0; k < kK; ++k) pk[qt][k] = 0.f;

  const int dt0 = w * 8;
  bf8v An[4];
  #pragma unroll
  for (int kc = 0; kc < 4; ++kc)
    An[kc] = *(const bf8v*)&db[(size_t)(dt0 * 16 + lr) * kC + kc * 32 + g * 8];

  for (int dtl = 0; dtl < 8; ++dtl) {
    const int drow0 = (dt0 + dtl) * 16;
    bf8v Ac[4];
    #pragma unroll
    for (int kc = 0; kc < 4; ++kc) Ac[kc] = An[kc];
    if (dtl < 7) {
      #pragma unroll
      for (int kc = 0; kc < 4; ++kc)
        An[kc] = *(const bf8v*)&db[(size_t)(drow0 + 16 + lr) * kC + kc * 32 + g * 8];
    }
    f4v acc0 = (f4v)0.f, acc1 = (f4v)0.f;
    #pragma unroll
    for (int kc = 0; kc < 4; ++kc) {
      acc0 = __builtin_amdgcn_mfma_f32_16x16x32_bf16(Ac[kc], Bq[0][kc], acc0, 0, 0, 0);
      acc1 = __builtin_amdgcn_mfma_f32_16x16x32_bf16(Ac[kc], Bq[1][kc], acc1, 0, 0, 0);
    }
    // lane holds S[d = drow0+g*4+r][q = qt*16+lr], r=0..3
    float4 dmv = *(const float4*)&dmask[b * kD + drow0 + g * 4];
    #pragma unroll
    for (int qt = 0; qt < 2; ++qt) {
      const f4v& a = qt ? acc1 : acc0;
      #pragma unroll
      for (int r = 0; r < 4; ++r) {
        float dm = (r == 0) ? dmv.x : (r == 1) ? dmv.y : (r == 2) ? dmv.z : dmv.w;
        float off = fmaf(dm, 1000.f, -1000.f);      // 0 if dm=1, -1000 if dm=0
        float s = a[r] * qmv[qt] * dm;              // masked cosine
        float s2 = s * s;
        float base = fmaf(s2, C50, off);
        // k=0 (mu=1, sigma=1e-3)
        float dd = s - 1.f;
        pk[qt][0] += exp2f(fmaf(dd * dd, C0, off));
        #pragma unroll
        for (int k = 0; k < 10; ++k)
          pk[qt][k + 1] += exp2f(fmaf(c1[k], s, base) + c2[k]);
      }
    }
  }

  // reduce over g-groups (lanes xor 16, 32)
  #pragma unroll
  for (int off = 16; off < 64; off <<= 1)
    #pragma unroll
    for (int qt = 0; qt < 2; ++qt)
      #pragma unroll
      for (int k = 0; k < kK; ++k)
        pk[qt][k] += __shfl_xor(pk[qt][k], off);

  if (l < 16) {
    #pragma unroll
    for (int qt = 0; qt < 2; ++qt)
      #pragma unroll
      for (int k = 0; k < kK; ++k)
        red[w][qt][lr][k] = pk[qt][k];
  }
  __syncthreads();
  for (int i = t; i < 2 * 16 * kK; i += 256) {
    int qt = i / (16 * kK);
    int rem = i - qt * 16 * kK;
    int lq = rem / kK, k = rem - lq * kK;
    float v = red[0][qt][lq][k] + red[1][qt][lq][k] + red[2][qt][lq][k] + red[3][qt][lq][k];
    int q = qt * 16 + lq;
    pkq[(((size_t)pair * kB + b) * kQ + q) * kK + k] = v * qmask[b * kQ + q];
  }
}

// ---------------- log-pool + dense layers ----------------
__global__ __launch_bounds__(128) void finalize_kernel(
    const float* __restrict__ pkq, const float* __restrict__ qmask,
    const float* __restrict__ dmask, const float* __restrict__ nsp,
    const float* __restrict__ dw, const float* __restrict__ dbp,
    const float* __restrict__ dmw, const float* __restrict__ dmbp,
    const float* __restrict__ dcw, float* __restrict__ out)
{
  const int b = blockIdx.x;
  const int t = threadIdx.x;
  __shared__ float sh[4];
  float dl = 0.f;
  for (int d = t; d < kD; d += 128) dl += dmask[b * kD + d];
  #pragma unroll
  for (int off = 1; off < 64; off <<= 1) dl += __shfl_xor(dl, off);
  if ((t & 63) == 0) sh[t >> 6] = dl;
  __syncthreads();
  const float idl = 1.f / (sh[0] + sh[1]);
  const float sc = nsp[0];
  float ps = 0.f, pm = 0.f;
  for (int i = t; i < 99; i += 128) {
    int pr = i / kK, kk = i - pr * kK;
    const float* base = pkq + ((size_t)pr * kB + b) * kQ * kK + kk;
    float ss = 0.f, sm = 0.f;
    for (int q = 0; q < kQ; ++q) {
      float v = base[q * kK];
      float qq = qmask[b * kQ + q];
      ss += __logf(fmaxf(v, 1e-10f)) * qq;
      sm += __logf(fmaxf(v * idl, 1e-10f)) * qq;
    }
    ps += dw[i] * ss;
    pm += dmw[i] * sm;
  }
  ps *= sc; pm *= sc;
  #pragma unroll
  for (int off = 1; off < 64; off <<= 1) { ps += __shfl_xor(ps, off); pm += __shfl_xor(pm, off); }
  __syncthreads();
  if ((t & 63) == 0) { sh[t >> 6] = ps; sh[2 + (t >> 6)] = pm; }
  __syncthreads();
  if (t == 0) {
    float PS = sh[0] + sh[1] + dbp[0];
    float PM = sh[2] + sh[3] + dmbp[0];
    out[b] = dcw[0] * PS + dcw[1] * PM;
  }
}

} // namespace

extern "C" void kernel_launch(void* const* d_in, const int* in_sizes, int n_in,
                              void* d_out, int out_size, void* d_ws, size_t ws_size,
                              hipStream_t stream) {
  const float* qe  = (const float*)d_in[0];
  const float* de  = (const float*)d_in[1];
  const float* qm  = (const float*)d_in[2];
  const float* dm  = (const float*)d_in[3];
  const float* w1  = (const float*)d_in[4];
  const float* b1  = (const float*)d_in[5];
  const float* w2  = (const float*)d_in[6];
  const float* b2  = (const float*)d_in[7];
  const float* w3  = (const float*)d_in[8];
  const float* b3  = (const float*)d_in[9];
  const float* ns  = (const float*)d_in[10];
  const float* dw  = (const float*)d_in[11];
  const float* db  = (const float*)d_in[12];
  const float* dmw = (const float*)d_in[13];
  const float* dmb = (const float*)d_in[14];
  const float* dcw = (const float*)d_in[15];
  float* out = (float*)d_out;

  char* wsb = (char*)d_ws;
  __bf16* wb  = (__bf16*)wsb;
  __bf16* qnb = (__bf16*)(wsb + QNB_B);
  __bf16* dnb = (__bf16*)(wsb + DNB_B);
  float*  pkq = (float*)(wsb + PKQ_B);

  prep_kernel<<<960, 256, 0, stream>>>(w1, w2, w3, wb);
  conv_fused<<<dim3(9, kB), 256, 0, stream>>>(qe, de, wb, b1, b2, b3, qnb, dnb);
  pool_mfma<<<dim3(9, kB), 256, 0, stream>>>(qnb, dnb, qm, dm, pkq);
  finalize_kernel<<<kB, 128, 0, stream>>>(pkq, qm, dm, ns, dw, db, dmw, dmb, dcw, out);
}

// Round 4
// 183.198 us; speedup vs baseline: 5.7596x; 1.4402x over previous
//
#include <hip/hip_runtime.h>
#include <hip/hip_bf16.h>
#include <cstdint>

namespace {

typedef __bf16 bf8v __attribute__((ext_vector_type(8)));
typedef __bf16 bf4v __attribute__((ext_vector_type(4)));
typedef float  f4v  __attribute__((ext_vector_type(4)));

constexpr int kB = 128;   // batch
constexpr int kQ = 32;    // query len
constexpr int kD = 512;   // doc len
constexpr int kE = 300;   // embed dim
constexpr int kC = 128;   // conv channels
constexpr int kK = 11;    // RBF kernels

// workspace layout (bytes)
// wb:  [6 slabs][10 ks][128 c][32 e] bf16 = 491520 B (slabs: c1j0 | c2j0 c2j1 | c3j0 c3j1 c3j2)
// qnb: [3][B][32][128]  bf16 = 3.1 MB  (position-major, normalized)
// dnb: [3][B][512][128] bf16 = 50.3 MB
// pkq: [9][B][32][11]   f32  = 1.6 MB
constexpr size_t QNB_B = 491520;
constexpr size_t DNB_B = 3637248;
constexpr size_t PKQ_B = 53968896;

constexpr float LOG2E = 1.4426950408889634f;

constexpr int XS_STRIDE = 344;   // elems; 688 B: 16B-aligned, 12-bank row offset

// ---------------- weight repack to bf16 [slab][ks][c][32] ----------------
__global__ __launch_bounds__(256) void prep_kernel(
    const float* __restrict__ w1, const float* __restrict__ w2, const float* __restrict__ w3,
    __bf16* __restrict__ wb)
{
  int i = blockIdx.x * 256 + threadIdx.x;   // 0..245759
  if (i >= 245760) return;
  int el = i & 31;
  int sc = i >> 5;              // (slab*10 + ks)*128 + c
  int c  = sc & 127;
  int sk = sc >> 7;             // slab*10 + ks
  int slab = sk / 10;
  int ks = sk - slab * 10;
  int e = ks * 32 + el;
  float v = 0.f;
  if (e < kE) {
    if (slab == 0)      v = w1[c * kE + e];
    else if (slab <= 2) v = w2[(c * kE + e) * 2 + (slab - 1)];
    else                v = w3[(c * kE + e) * 3 + (slab - 3)];
  }
  wb[i] = (__bf16)v;
}

// ---------------- per-slab-group MFMA loop with depth-1 register prefetch ----------------
template<int KF>
__device__ __forceinline__ void conv_slab(
    const __bf16* __restrict__ wslab,   // wb + slab0*40960
    const __bf16* __restrict__ Xs,
    int lr, int g, int wm, int wn, f4v acc[2][4])
{
  const int arow = wm * 32 + lr;
  const __bf16* wl = wslab + (size_t)(wn * 64 + lr) * 32 + g * 8;

  bf8v An[2], Wn[4];
  #pragma unroll
  for (int mf = 0; mf < 2; ++mf)
    An[mf] = *(const bf8v*)&Xs[(arow + mf * 16) * XS_STRIDE + g * 8];
  #pragma unroll
  for (int nf = 0; nf < 4; ++nf)
    Wn[nf] = *(const bf8v*)(wl + (size_t)(nf * 16) * 32);

  for (int ks = 0; ks < 10; ++ks) {
    #pragma unroll
    for (int j = 0; j < KF; ++j) {
      bf8v Ac[2] = { An[0], An[1] };
      bf8v Wc[4] = { Wn[0], Wn[1], Wn[2], Wn[3] };
      const int jn  = (j + 1 == KF) ? 0 : j + 1;
      const int ksn = (j + 1 == KF) ? ks + 1 : ks;
      if (ksn < 10) {
        #pragma unroll
        for (int mf = 0; mf < 2; ++mf)
          An[mf] = *(const bf8v*)&Xs[(arow + mf * 16 + jn) * XS_STRIDE + ksn * 32 + g * 8];
        #pragma unroll
        for (int nf = 0; nf < 4; ++nf)
          Wn[nf] = *(const bf8v*)(wl + ((size_t)(jn * 10 + ksn) * 128 + nf * 16) * 32);
      }
      #pragma unroll
      for (int nf = 0; nf < 4; ++nf) {
        acc[0][nf] = __builtin_amdgcn_mfma_f32_16x16x32_bf16(Ac[0], Wc[nf], acc[0][nf], 0, 0, 0);
        acc[1][nf] = __builtin_amdgcn_mfma_f32_16x16x32_bf16(Ac[1], Wc[nf], acc[1][nf], 0, 0, 0);
      }
    }
  }
}

// ---------------- fused conv (all 3 widths) + bias + relu + L2-norm -> bf16 [L][C] ----------------
// grid (9, B): x==0 -> query (L=32), x=1..8 -> doc tile (p0=(x-1)*64, L=512)
// 256 threads = 4 waves; tile 64 pos x 128 ch; wave (wm,wn) -> rows wm*32+, cols wn*64+
__global__ __launch_bounds__(256, 3) void conv_fused(
    const float* __restrict__ qe, const float* __restrict__ de,
    const __bf16* __restrict__ wb,
    const float* __restrict__ b1, const float* __restrict__ b2, const float* __restrict__ b3,
    __bf16* __restrict__ qnb, __bf16* __restrict__ dnb)
{
  const int bx = blockIdx.x;
  const int b  = blockIdx.y;
  const bool isq = (bx == 0);
  const int L  = isq ? kQ : kD;
  const int p0 = isq ? 0 : (bx - 1) * 64;
  const float* xsrc = (isq ? qe : de) + (size_t)b * L * kE;

  const int t = threadIdx.x;
  const int w = t >> 6, l = t & 63;
  const int wm = w & 1, wn = w >> 1;
  const int lr = l & 15, g = l >> 4;

  __shared__ __align__(16) __bf16 Xs[66 * XS_STRIDE];
  __shared__ float sqs[2][64];

  // stage x rows p0..p0+65, e 0..327 (zero-pad) as bf16
  for (int idx = t; idx < 66 * 82; idx += 256) {
    int row = idx / 82, c4 = idx - row * 82;
    int gp = p0 + row;
    float4 v = make_float4(0.f, 0.f, 0.f, 0.f);
    if (gp < L && c4 < 75) v = *(const float4*)(xsrc + (size_t)gp * kE + c4 * 4);
    bf4v hv = { (__bf16)v.x, (__bf16)v.y, (__bf16)v.z, (__bf16)v.w };
    *(bf4v*)&Xs[row * XS_STRIDE + c4 * 4] = hv;
  }
  __syncthreads();

  #pragma unroll
  for (int c0 = 0; c0 < 3; ++c0) {
    f4v acc[2][4];
    #pragma unroll
    for (int mf = 0; mf < 2; ++mf)
      #pragma unroll
      for (int nf = 0; nf < 4; ++nf)
        acc[mf][nf] = (f4v)0.f;

    if (c0 == 0)      conv_slab<1>(wb,           Xs, lr, g, wm, wn, acc);
    else if (c0 == 1) conv_slab<2>(wb + 40960,   Xs, lr, g, wm, wn, acc);
    else              conv_slab<3>(wb + 122880,  Xs, lr, g, wm, wn, acc);

    // epilogue: bias + relu + L2 norm over 128 channels
    const float* bias = (c0 == 0) ? b1 : ((c0 == 1) ? b2 : b3);
    float bvs[4];
    #pragma unroll
    for (int nf = 0; nf < 4; ++nf) bvs[nf] = bias[wn * 64 + nf * 16 + lr];

    f4v ssum[2];
    #pragma unroll
    for (int mf = 0; mf < 2; ++mf) {
      ssum[mf] = (f4v)0.f;
      #pragma unroll
      for (int nf = 0; nf < 4; ++nf)
        #pragma unroll
        for (int r = 0; r < 4; ++r) {
          float y = fmaxf(acc[mf][nf][r] + bvs[nf], 0.f);
          acc[mf][nf][r] = y;
          ssum[mf][r] += y * y;
        }
    }
    #pragma unroll
    for (int off = 1; off < 16; off <<= 1)
      #pragma unroll
      for (int mf = 0; mf < 2; ++mf)
        #pragma unroll
        for (int r = 0; r < 4; ++r)
          ssum[mf][r] += __shfl_xor(ssum[mf][r], off);

    __syncthreads();              // sqs reuse across c0 iterations
    if (lr == 0) {
      #pragma unroll
      for (int mf = 0; mf < 2; ++mf)
        *(float4*)&sqs[wn][wm * 32 + mf * 16 + g * 4] = *(float4*)&ssum[mf];
    }
    __syncthreads();
    f4v inv[2];
    #pragma unroll
    for (int mf = 0; mf < 2; ++mf) {
      float4 o = *(const float4*)&sqs[1 - wn][wm * 32 + mf * 16 + g * 4];
      inv[mf][0] = 1.f / (sqrtf(ssum[mf][0] + o.x) + 1e-13f);
      inv[mf][1] = 1.f / (sqrtf(ssum[mf][1] + o.y) + 1e-13f);
      inv[mf][2] = 1.f / (sqrtf(ssum[mf][2] + o.z) + 1e-13f);
      inv[mf][3] = 1.f / (sqrtf(ssum[mf][3] + o.w) + 1e-13f);
    }
    // store bf16 [B][L][C]
    __bf16* outp = (isq ? qnb : dnb) + ((size_t)(c0 * kB + b)) * L * kC;
    #pragma unroll
    for (int mf = 0; mf < 2; ++mf) {
      #pragma unroll
      for (int r = 0; r < 4; ++r) {
        int gp = p0 + wm * 32 + mf * 16 + g * 4 + r;
        if (gp < L) {
          #pragma unroll
          for (int nf = 0; nf < 4; ++nf) {
            int c = wn * 64 + nf * 16 + lr;
            outp[(size_t)gp * kC + c] = (__bf16)(acc[mf][nf][r] * inv[mf][r]);
          }
        }
      }
    }
  }
}

// ---------------- MFMA cosine + RBF pooling ----------------
// grid (9, B), 256 threads = 4 waves. Per block: S[512 d][32 q] for one (pair,b).
__global__ __launch_bounds__(256) void pool_mfma(
    const __bf16* __restrict__ qnb,  // [3][B][32][128]
    const __bf16* __restrict__ dnb,  // [3][B][512][128]
    const float* __restrict__ qmask, // [B][32]
    const float* __restrict__ dmask, // [B][512]
    float* __restrict__ pkq)         // [9][B][32][11]
{
  const int pair = blockIdx.x;
  const int b = blockIdx.y;
  const int qi = pair / 3, dj = pair - qi * 3;
  const __bf16* qb = qnb + ((size_t)qi * kB + b) * kQ * kC;
  const __bf16* db = dnb + ((size_t)dj * kB + b) * kD * kC;

  const int t = threadIdx.x;
  const int w = t >> 6, l = t & 63;
  const int lr = l & 15, g = l >> 4;

  __shared__ float red[4][2][16][kK];

  bf8v Bq[2][4];
  #pragma unroll
  for (int qt = 0; qt < 2; ++qt)
    #pragma unroll
    for (int kc = 0; kc < 4; ++kc)
      Bq[qt][kc] = *(const bf8v*)&qb[(size_t)(qt * 16 + lr) * kC + kc * 32 + g * 8];

  float qmv[2];
  #pragma unroll
  for (int qt = 0; qt < 2; ++qt) qmv[qt] = qmask[b * kQ + qt * 16 + lr];

  const float c1[10] = { 129.84255368f, 100.98865286f,  72.13475204f,  43.28085123f,  14.42695041f,
                         -14.42695041f, -43.28085123f, -72.13475204f, -100.98865286f, -129.84255368f };
  const float c2[10] = { -58.42914915f, -35.34602850f, -18.03368801f, -6.49212768f, -0.72134752f,
                          -0.72134752f,  -6.49212768f, -18.03368801f, -35.34602850f, -58.42914915f };
  const float C50 = -50.f * LOG2E;
  const float C0  = -500000.f * LOG2E;

  float pk[2][kK];
  #pragma unroll
  for (int qt = 0; qt < 2; ++qt)
    #pragma unroll
    for (int k = 0; k < kK; ++k) pk[qt][k] = 0.f;

  const int dt0 = w * 8;
  bf8v An[4];
  #pragma unroll
  for (int kc = 0; kc < 4; ++kc)
    An[kc] = *(const bf8v*)&db[(size_t)(dt0 * 16 + lr) * kC + kc * 32 + g * 8];

  for (int dtl = 0; dtl < 8; ++dtl) {
    const int drow0 = (dt0 + dtl) * 16;
    bf8v Ac[4];
    #pragma unroll
    for (int kc = 0; kc < 4; ++kc) Ac[kc] = An[kc];
    if (dtl < 7) {
      #pragma unroll
      for (int kc = 0; kc < 4; ++kc)
        An[kc] = *(const bf8v*)&db[(size_t)(drow0 + 16 + lr) * kC + kc * 32 + g * 8];
    }
    f4v acc0 = (f4v)0.f, acc1 = (f4v)0.f;
    #pragma unroll
    for (int kc = 0; kc < 4; ++kc) {
      acc0 = __builtin_amdgcn_mfma_f32_16x16x32_bf16(Ac[kc], Bq[0][kc], acc0, 0, 0, 0);
      acc1 = __builtin_amdgcn_mfma_f32_16x16x32_bf16(Ac[kc], Bq[1][kc], acc1, 0, 0, 0);
    }
    float4 dmv = *(const float4*)&dmask[b * kD + drow0 + g * 4];
    #pragma unroll
    for (int qt = 0; qt < 2; ++qt) {
      const f4v& a = qt ? acc1 : acc0;
      #pragma unroll
      for (int r = 0; r < 4; ++r) {
        float dm = (r == 0) ? dmv.x : (r == 1) ? dmv.y : (r == 2) ? dmv.z : dmv.w;
        float off = fmaf(dm, 1000.f, -1000.f);
        float s = a[r] * qmv[qt] * dm;
        float s2 = s * s;
        float base = fmaf(s2, C50, off);
        float dd = s - 1.f;
        pk[qt][0] += exp2f(fmaf(dd * dd, C0, off));
        #pragma unroll
        for (int k = 0; k < 10; ++k)
          pk[qt][k + 1] += exp2f(fmaf(c1[k], s, base) + c2[k]);
      }
    }
  }

  #pragma unroll
  for (int off = 16; off < 64; off <<= 1)
    #pragma unroll
    for (int qt = 0; qt < 2; ++qt)
      #pragma unroll
      for (int k = 0; k < kK; ++k)
        pk[qt][k] += __shfl_xor(pk[qt][k], off);

  if (l < 16) {
    #pragma unroll
    for (int qt = 0; qt < 2; ++qt)
      #pragma unroll
      for (int k = 0; k < kK; ++k)
        red[w][qt][lr][k] = pk[qt][k];
  }
  __syncthreads();
  for (int i = t; i < 2 * 16 * kK; i += 256) {
    int qt = i / (16 * kK);
    int rem = i - qt * 16 * kK;
    int lq = rem / kK, k = rem - lq * kK;
    float v = red[0][qt][lq][k] + red[1][qt][lq][k] + red[2][qt][lq][k] + red[3][qt][lq][k];
    int q = qt * 16 + lq;
    pkq[(((size_t)pair * kB + b) * kQ + q) * kK + k] = v * qmask[b * kQ + q];
  }
}

// ---------------- log-pool + dense layers ----------------
__global__ __launch_bounds__(128) void finalize_kernel(
    const float* __restrict__ pkq, const float* __restrict__ qmask,
    const float* __restrict__ dmask, const float* __restrict__ nsp,
    const float* __restrict__ dw, const float* __restrict__ dbp,
    const float* __restrict__ dmw, const float* __restrict__ dmbp,
    const float* __restrict__ dcw, float* __restrict__ out)
{
  const int b = blockIdx.x;
  const int t = threadIdx.x;
  __shared__ float sh[4];
  float dl = 0.f;
  for (int d = t; d < kD; d += 128) dl += dmask[b * kD + d];
  #pragma unroll
  for (int off = 1; off < 64; off <<= 1) dl += __shfl_xor(dl, off);
  if ((t & 63) == 0) sh[t >> 6] = dl;
  __syncthreads();
  const float idl = 1.f / (sh[0] + sh[1]);
  const float sc = nsp[0];
  float ps = 0.f, pm = 0.f;
  for (int i = t; i < 99; i += 128) {
    int pr = i / kK, kk = i - pr * kK;
    const float* base = pkq + ((size_t)pr * kB + b) * kQ * kK + kk;
    float ss = 0.f, sm = 0.f;
    for (int q = 0; q < kQ; ++q) {
      float v = base[q * kK];
      float qq = qmask[b * kQ + q];
      ss += __logf(fmaxf(v, 1e-10f)) * qq;
      sm += __logf(fmaxf(v * idl, 1e-10f)) * qq;
    }
    ps += dw[i] * ss;
    pm += dmw[i] * sm;
  }
  ps *= sc; pm *= sc;
  #pragma unroll
  for (int off = 1; off < 64; off <<= 1) { ps += __shfl_xor(ps, off); pm += __shfl_xor(pm, off); }
  __syncthreads();
  if ((t & 63) == 0) { sh[t >> 6] = ps; sh[2 + (t >> 6)] = pm; }
  __syncthreads();
  if (t == 0) {
    float PS = sh[0] + sh[1] + dbp[0];
    float PM = sh[2] + sh[3] + dmbp[0];
    out[b] = dcw[0] * PS + dcw[1] * PM;
  }
}

} // namespace

extern "C" void kernel_launch(void* const* d_in, const int* in_sizes, int n_in,
                              void* d_out, int out_size, void* d_ws, size_t ws_size,
                              hipStream_t stream) {
  const float* qe  = (const float*)d_in[0];
  const float* de  = (const float*)d_in[1];
  const float* qm  = (const float*)d_in[2];
  const float* dm  = (const float*)d_in[3];
  const float* w1  = (const float*)d_in[4];
  const float* b1  = (const float*)d_in[5];
  const float* w2  = (const float*)d_in[6];
  const float* b2  = (const float*)d_in[7];
  const float* w3  = (const float*)d_in[8];
  const float* b3  = (const float*)d_in[9];
  const float* ns  = (const float*)d_in[10];
  const float* dw  = (const float*)d_in[11];
  const float* db  = (const float*)d_in[12];
  const float* dmw = (const float*)d_in[13];
  const float* dmb = (const float*)d_in[14];
  const float* dcw = (const float*)d_in[15];
  float* out = (float*)d_out;

  char* wsb = (char*)d_ws;
  __bf16* wb  = (__bf16*)wsb;
  __bf16* qnb = (__bf16*)(wsb + QNB_B);
  __bf16* dnb = (__bf16*)(wsb + DNB_B);
  float*  pkq = (float*)(wsb + PKQ_B);

  prep_kernel<<<960, 256, 0, stream>>>(w1, w2, w3, wb);
  conv_fused<<<dim3(9, kB), 256, 0, stream>>>(qe, de, wb, b1, b2, b3, qnb, dnb);
  pool_mfma<<<dim3(9, kB), 256, 0, stream>>>(qnb, dnb, qm, dm, pkq);
  finalize_kernel<<<kB, 128, 0, stream>>>(pkq, qm, dm, ns, dw, db, dmw, dmb, dcw, out);
}

// Round 5
// 162.432 us; speedup vs baseline: 6.4960x; 1.1278x over previous
//
#include <hip/hip_runtime.h>
#include <hip/hip_bf16.h>
#include <cstdint>

namespace {

typedef __bf16 bf8v __attribute__((ext_vector_type(8)));
typedef __bf16 bf4v __attribute__((ext_vector_type(4)));
typedef float  f4v  __attribute__((ext_vector_type(4)));

constexpr int kB = 128;   // batch
constexpr int kQ = 32;    // query len
constexpr int kD = 512;   // doc len
constexpr int kE = 300;   // embed dim
constexpr int kC = 128;   // conv channels
constexpr int kK = 11;    // RBF kernels

// workspace layout (bytes)
// wb:  [6 slabs][10 ks][128 c][32 e] bf16 = 491520 B (slabs: c1j0 | c2j0 c2j1 | c3j0 c3j1 c3j2)
// qnb: [3][B][32][128]  bf16   dnb: [3][B][512][128] bf16   pkq: [9][B][32][11] f32
constexpr size_t QNB_B = 491520;
constexpr size_t DNB_B = 3637248;
constexpr size_t PKQ_B = 53968896;

constexpr float LOG2E = 1.4426950408889634f;

constexpr int XS_STRIDE = 344;   // elems; 688 B row stride
constexpr int WS_STRIDE = 40;    // elems; 80 B row stride (32 data + 8 pad), 16B-aligned

// ---------------- weight repack to bf16 [slab][ks][c][32] ----------------
__global__ __launch_bounds__(256) void prep_kernel(
    const float* __restrict__ w1, const float* __restrict__ w2, const float* __restrict__ w3,
    __bf16* __restrict__ wb)
{
  int i = blockIdx.x * 256 + threadIdx.x;   // 0..245759
  if (i >= 245760) return;
  int el = i & 31;
  int sc = i >> 5;              // (slab*10 + ks)*128 + c
  int c  = sc & 127;
  int sk = sc >> 7;             // slab*10 + ks
  int slab = sk / 10;
  int ks = sk - slab * 10;
  int e = ks * 32 + el;
  float v = 0.f;
  if (e < kE) {
    if (slab == 0)      v = w1[c * kE + e];
    else if (slab <= 2) v = w2[(c * kE + e) * 2 + (slab - 1)];
    else                v = w3[(c * kE + e) * 3 + (slab - 3)];
  }
  wb[i] = (__bf16)v;
}

// one pipeline step: issue chunk s+2 -> (na,nb); compute from Wcur; write (ra,rb)=chunk s+1 -> Wnxt
__device__ __forceinline__ void conv_step(
    const __bf16* __restrict__ Xs,
    const __bf16* __restrict__ Wcur, __bf16* __restrict__ Wnxt,
    const uint4* __restrict__ wsrc, bool issue_next, bool do_write,
    uint4& ra, uint4& rb, uint4& na, uint4& nb,
    int u0, int u1, int wst0, int wst1,
    int a0, int a1, int wfoff, f4v (&acc)[2][4])
{
  if (issue_next) { na = wsrc[u0]; nb = wsrc[u1]; }
  bf8v A0 = *(const bf8v*)(Xs + a0);
  bf8v A1 = *(const bf8v*)(Xs + a1);
  const __bf16* wp = Wcur + wfoff;
  bf8v W0 = *(const bf8v*)(wp);
  bf8v W1 = *(const bf8v*)(wp + 16 * WS_STRIDE);
  bf8v W2 = *(const bf8v*)(wp + 32 * WS_STRIDE);
  bf8v W3 = *(const bf8v*)(wp + 48 * WS_STRIDE);
  acc[0][0] = __builtin_amdgcn_mfma_f32_16x16x32_bf16(A0, W0, acc[0][0], 0, 0, 0);
  acc[1][0] = __builtin_amdgcn_mfma_f32_16x16x32_bf16(A1, W0, acc[1][0], 0, 0, 0);
  acc[0][1] = __builtin_amdgcn_mfma_f32_16x16x32_bf16(A0, W1, acc[0][1], 0, 0, 0);
  acc[1][1] = __builtin_amdgcn_mfma_f32_16x16x32_bf16(A1, W1, acc[1][1], 0, 0, 0);
  acc[0][2] = __builtin_amdgcn_mfma_f32_16x16x32_bf16(A0, W2, acc[0][2], 0, 0, 0);
  acc[1][2] = __builtin_amdgcn_mfma_f32_16x16x32_bf16(A1, W2, acc[1][2], 0, 0, 0);
  acc[0][3] = __builtin_amdgcn_mfma_f32_16x16x32_bf16(A0, W3, acc[0][3], 0, 0, 0);
  acc[1][3] = __builtin_amdgcn_mfma_f32_16x16x32_bf16(A1, W3, acc[1][3], 0, 0, 0);
  if (do_write) {
    *(uint4*)(Wnxt + wst0) = ra;
    *(uint4*)(Wnxt + wst1) = rb;
  }
  __syncthreads();
}

// ---------------- fused conv (all 3 widths) + bias + relu + L2-norm -> bf16 [L][C] ----------------
// grid (9, B): x==0 -> query (L=32), x=1..8 -> doc tile (p0=(x-1)*64)
// 256 threads = 4 waves; tile 64 pos x 128 ch; wave (wm,wn) -> rows wm*32+, cols wn*64+
__global__ __launch_bounds__(256) void conv_fused(
    const float* __restrict__ qe, const float* __restrict__ de,
    const __bf16* __restrict__ wb,
    const float* __restrict__ b1, const float* __restrict__ b2, const float* __restrict__ b3,
    __bf16* __restrict__ qnb, __bf16* __restrict__ dnb)
{
  const int bx = blockIdx.x;
  const int b  = blockIdx.y;
  const bool isq = (bx == 0);
  const int L  = isq ? kQ : kD;
  const int p0 = isq ? 0 : (bx - 1) * 64;
  const float* xsrc = (isq ? qe : de) + (size_t)b * L * kE;

  const int t = threadIdx.x;
  const int w = t >> 6, l = t & 63;
  const int wm = w & 1, wn = w >> 1;
  const int lr = l & 15, g = l >> 4;

  __shared__ __align__(16) __bf16 Xs[66 * XS_STRIDE];
  __shared__ __align__(16) __bf16 Wbuf[2][128 * WS_STRIDE];
  __shared__ float sqs[2][64];

  // W staging indices
  const int u0 = t, u1 = t + 256;
  const int wst0 = (t >> 2) * WS_STRIDE + (t & 3) * 8;
  const int wst1 = ((t >> 2) + 64) * WS_STRIDE + (t & 3) * 8;
  const int wfoff = (wn * 64 + lr) * WS_STRIDE + g * 8;
  const uint4* wsrcb = (const uint4*)wb;      // chunk s = [s*512 .. s*512+512) uint4s

  uint4 r0a, r0b, r1a, r1b;
  r0a = wsrcb[u0];        r0b = wsrcb[u1];          // chunk 0
  r1a = wsrcb[512 + u0];  r1b = wsrcb[512 + u1];    // chunk 1

  // stage x rows p0..p0+65, e 0..327 (zero-pad) as bf16
  for (int idx = t; idx < 66 * 82; idx += 256) {
    int row = idx / 82, c4 = idx - row * 82;
    int gp = p0 + row;
    float4 v = make_float4(0.f, 0.f, 0.f, 0.f);
    if (gp < L && c4 < 75) v = *(const float4*)(xsrc + (size_t)gp * kE + c4 * 4);
    bf4v hv = { (__bf16)v.x, (__bf16)v.y, (__bf16)v.z, (__bf16)v.w };
    *(bf4v*)&Xs[row * XS_STRIDE + c4 * 4] = hv;
  }
  *(uint4*)(&Wbuf[0][0] + wst0) = r0a;
  *(uint4*)(&Wbuf[0][0] + wst1) = r0b;
  __syncthreads();

  #pragma unroll
  for (int grp = 0; grp < 3; ++grp) {
    f4v acc[2][4];
    #pragma unroll
    for (int mf = 0; mf < 2; ++mf)
      #pragma unroll
      for (int nf = 0; nf < 4; ++nf)
        acc[mf][nf] = (f4v)0.f;

    #pragma unroll
    for (int j = 0; j <= grp; ++j) {
      const int slab = grp * (grp + 1) / 2 + j;
      const int abase = (wm * 32 + lr + j) * XS_STRIDE + g * 8;
      #pragma unroll
      for (int ks = 0; ks < 10; ++ks) {
        const int s = slab * 10 + ks;
        const bool issue = (s + 2 < 60);
        const bool wr    = (s + 1 < 60);
        const int a0 = abase + ks * 32;
        const int a1 = a0 + 16 * XS_STRIDE;
        if ((s & 1) == 0)
          conv_step(Xs, &Wbuf[0][0], &Wbuf[1][0], wsrcb + (size_t)(s + 2) * 512, issue, wr,
                    r1a, r1b, r0a, r0b, u0, u1, wst0, wst1, a0, a1, wfoff, acc);
        else
          conv_step(Xs, &Wbuf[1][0], &Wbuf[0][0], wsrcb + (size_t)(s + 2) * 512, issue, wr,
                    r0a, r0b, r1a, r1b, u0, u1, wst0, wst1, a0, a1, wfoff, acc);
      }
    }

    // epilogue: bias + relu + L2 norm over 128 channels
    const float* bias = (grp == 0) ? b1 : ((grp == 1) ? b2 : b3);
    float bvs[4];
    #pragma unroll
    for (int nf = 0; nf < 4; ++nf) bvs[nf] = bias[wn * 64 + nf * 16 + lr];

    f4v ssum[2];
    #pragma unroll
    for (int mf = 0; mf < 2; ++mf) {
      ssum[mf] = (f4v)0.f;
      #pragma unroll
      for (int nf = 0; nf < 4; ++nf)
        #pragma unroll
        for (int r = 0; r < 4; ++r) {
          float y = fmaxf(acc[mf][nf][r] + bvs[nf], 0.f);
          acc[mf][nf][r] = y;
          ssum[mf][r] += y * y;
        }
    }
    #pragma unroll
    for (int off = 1; off < 16; off <<= 1)
      #pragma unroll
      for (int mf = 0; mf < 2; ++mf)
        #pragma unroll
        for (int r = 0; r < 4; ++r)
          ssum[mf][r] += __shfl_xor(ssum[mf][r], off);

    __syncthreads();
    if (lr == 0) {
      #pragma unroll
      for (int mf = 0; mf < 2; ++mf)
        *(float4*)&sqs[wn][wm * 32 + mf * 16 + g * 4] = *(float4*)&ssum[mf];
    }
    __syncthreads();
    f4v inv[2];
    #pragma unroll
    for (int mf = 0; mf < 2; ++mf) {
      float4 o = *(const float4*)&sqs[1 - wn][wm * 32 + mf * 16 + g * 4];
      inv[mf][0] = 1.f / (sqrtf(ssum[mf][0] + o.x) + 1e-13f);
      inv[mf][1] = 1.f / (sqrtf(ssum[mf][1] + o.y) + 1e-13f);
      inv[mf][2] = 1.f / (sqrtf(ssum[mf][2] + o.z) + 1e-13f);
      inv[mf][3] = 1.f / (sqrtf(ssum[mf][3] + o.w) + 1e-13f);
    }
    // store bf16 [B][L][C]
    __bf16* outp = (isq ? qnb : dnb) + ((size_t)(grp * kB + b)) * L * kC;
    #pragma unroll
    for (int mf = 0; mf < 2; ++mf) {
      #pragma unroll
      for (int r = 0; r < 4; ++r) {
        int gp = p0 + wm * 32 + mf * 16 + g * 4 + r;
        if (gp < L) {
          #pragma unroll
          for (int nf = 0; nf < 4; ++nf) {
            int c = wn * 64 + nf * 16 + lr;
            outp[(size_t)gp * kC + c] = (__bf16)(acc[mf][nf][r] * inv[mf][r]);
          }
        }
      }
    }
  }
}

// ---------------- MFMA cosine + RBF pooling ----------------
// grid (9, B), 256 threads = 4 waves. Per block: S[512 d][32 q] for one (pair,b).
__global__ __launch_bounds__(256) void pool_mfma(
    const __bf16* __restrict__ qnb,  // [3][B][32][128]
    const __bf16* __restrict__ dnb,  // [3][B][512][128]
    const float* __restrict__ qmask, // [B][32]
    const float* __restrict__ dmask, // [B][512]
    float* __restrict__ pkq)         // [9][B][32][11]
{
  const int pair = blockIdx.x;
  const int b = blockIdx.y;
  const int qi = pair / 3, dj = pair - qi * 3;
  const __bf16* qb = qnb + ((size_t)qi * kB + b) * kQ * kC;
  const __bf16* db = dnb + ((size_t)dj * kB + b) * kD * kC;

  const int t = threadIdx.x;
  const int w = t >> 6, l = t & 63;
  const int lr = l & 15, g = l >> 4;

  __shared__ float red[4][2][16][kK];

  bf8v Bq[2][4];
  #pragma unroll
  for (int qt = 0; qt < 2; ++qt)
    #pragma unroll
    for (int kc = 0; kc < 4; ++kc)
      Bq[qt][kc] = *(const bf8v*)&qb[(size_t)(qt * 16 + lr) * kC + kc * 32 + g * 8];

  float qmv[2];
  #pragma unroll
  for (int qt = 0; qt < 2; ++qt) qmv[qt] = qmask[b * kQ + qt * 16 + lr];

  const float c1[10] = { 129.84255368f, 100.98865286f,  72.13475204f,  43.28085123f,  14.42695041f,
                         -14.42695041f, -43.28085123f, -72.13475204f, -100.98865286f, -129.84255368f };
  const float c2[10] = { -58.42914915f, -35.34602850f, -18.03368801f, -6.49212768f, -0.72134752f,
                          -0.72134752f,  -6.49212768f, -18.03368801f, -35.34602850f, -58.42914915f };
  const float C50 = -50.f * LOG2E;
  const float C0  = -500000.f * LOG2E;

  float pk[2][kK];
  #pragma unroll
  for (int qt = 0; qt < 2; ++qt)
    #pragma unroll
    for (int k = 0; k < kK; ++k) pk[qt][k] = 0.f;

  const int dt0 = w * 8;
  bf8v An[4];
  #pragma unroll
  for (int kc = 0; kc < 4; ++kc)
    An[kc] = *(const bf8v*)&db[(size_t)(dt0 * 16 + lr) * kC + kc * 32 + g * 8];

  for (int dtl = 0; dtl < 8; ++dtl) {
    const int drow0 = (dt0 + dtl) * 16;
    bf8v Ac[4];
    #pragma unroll
    for (int kc = 0; kc < 4; ++kc) Ac[kc] = An[kc];
    if (dtl < 7) {
      #pragma unroll
      for (int kc = 0; kc < 4; ++kc)
        An[kc] = *(const bf8v*)&db[(size_t)(drow0 + 16 + lr) * kC + kc * 32 + g * 8];
    }
    f4v acc0 = (f4v)0.f, acc1 = (f4v)0.f;
    #pragma unroll
    for (int kc = 0; kc < 4; ++kc) {
      acc0 = __builtin_amdgcn_mfma_f32_16x16x32_bf16(Ac[kc], Bq[0][kc], acc0, 0, 0, 0);
      acc1 = __builtin_amdgcn_mfma_f32_16x16x32_bf16(Ac[kc], Bq[1][kc], acc1, 0, 0, 0);
    }
    float4 dmv = *(const float4*)&dmask[b * kD + drow0 + g * 4];
    #pragma unroll
    for (int qt = 0; qt < 2; ++qt) {
      const f4v& a = qt ? acc1 : acc0;
      #pragma unroll
      for (int r = 0; r < 4; ++r) {
        float dm = (r == 0) ? dmv.x : (r == 1) ? dmv.y : (r == 2) ? dmv.z : dmv.w;
        float off = fmaf(dm, 1000.f, -1000.f);
        float s = a[r] * qmv[qt] * dm;
        float s2 = s * s;
        float base = fmaf(s2, C50, off);
        float dd = s - 1.f;
        pk[qt][0] += exp2f(fmaf(dd * dd, C0, off));
        #pragma unroll
        for (int k = 0; k < 10; ++k)
          pk[qt][k + 1] += exp2f(fmaf(c1[k], s, base) + c2[k]);
      }
    }
  }

  #pragma unroll
  for (int off = 16; off < 64; off <<= 1)
    #pragma unroll
    for (int qt = 0; qt < 2; ++qt)
      #pragma unroll
      for (int k = 0; k < kK; ++k)
        pk[qt][k] += __shfl_xor(pk[qt][k], off);

  if (l < 16) {
    #pragma unroll
    for (int qt = 0; qt < 2; ++qt)
      #pragma unroll
      for (int k = 0; k < kK; ++k)
        red[w][qt][lr][k] = pk[qt][k];
  }
  __syncthreads();
  for (int i = t; i < 2 * 16 * kK; i += 256) {
    int qt = i / (16 * kK);
    int rem = i - qt * 16 * kK;
    int lq = rem / kK, k = rem - lq * kK;
    float v = red[0][qt][lq][k] + red[1][qt][lq][k] + red[2][qt][lq][k] + red[3][qt][lq][k];
    int q = qt * 16 + lq;
    pkq[(((size_t)pair * kB + b) * kQ + q) * kK + k] = v * qmask[b * kQ + q];
  }
}

// ---------------- log-pool + dense layers ----------------
__global__ __launch_bounds__(128) void finalize_kernel(
    const float* __restrict__ pkq, const float* __restrict__ qmask,
    const float* __restrict__ dmask, const float* __restrict__ nsp,
    const float* __restrict__ dw, const float* __restrict__ dbp,
    const float* __restrict__ dmw, const float* __restrict__ dmbp,
    const float* __restrict__ dcw, float* __restrict__ out)
{
  const int b = blockIdx.x;
  const int t = threadIdx.x;
  __shared__ float sh[4];
  float dl = 0.f;
  for (int d = t; d < kD; d += 128) dl += dmask[b * kD + d];
  #pragma unroll
  for (int off = 1; off < 64; off <<= 1) dl += __shfl_xor(dl, off);
  if ((t & 63) == 0) sh[t >> 6] = dl;
  __syncthreads();
  const float idl = 1.f / (sh[0] + sh[1]);
  const float sc = nsp[0];
  float ps = 0.f, pm = 0.f;
  for (int i = t; i < 99; i += 128) {
    int pr = i / kK, kk = i - pr * kK;
    const float* base = pkq + ((size_t)pr * kB + b) * kQ * kK + kk;
    float ss = 0.f, sm = 0.f;
    for (int q = 0; q < kQ; ++q) {
      float v = base[q * kK];
      float qq = qmask[b * kQ + q];
      ss += __logf(fmaxf(v, 1e-10f)) * qq;
      sm += __logf(fmaxf(v * idl, 1e-10f)) * qq;
    }
    ps += dw[i] * ss;
    pm += dmw[i] * sm;
  }
  ps *= sc; pm *= sc;
  #pragma unroll
  for (int off = 1; off < 64; off <<= 1) { ps += __shfl_xor(ps, off); pm += __shfl_xor(pm, off); }
  __syncthreads();
  if ((t & 63) == 0) { sh[t >> 6] = ps; sh[2 + (t >> 6)] = pm; }
  __syncthreads();
  if (t == 0) {
    float PS = sh[0] + sh[1] + dbp[0];
    float PM = sh[2] + sh[3] + dmbp[0];
    out[b] = dcw[0] * PS + dcw[1] * PM;
  }
}

} // namespace

extern "C" void kernel_launch(void* const* d_in, const int* in_sizes, int n_in,
                              void* d_out, int out_size, void* d_ws, size_t ws_size,
                              hipStream_t stream) {
  const float* qe  = (const float*)d_in[0];
  const float* de  = (const float*)d_in[1];
  const float* qm  = (const float*)d_in[2];
  const float* dm  = (const float*)d_in[3];
  const float* w1  = (const float*)d_in[4];
  const float* b1  = (const float*)d_in[5];
  const float* w2  = (const float*)d_in[6];
  const float* b2  = (const float*)d_in[7];
  const float* w3  = (const float*)d_in[8];
  const float* b3  = (const float*)d_in[9];
  const float* ns  = (const float*)d_in[10];
  const float* dw  = (const float*)d_in[11];
  const float* db  = (const float*)d_in[12];
  const float* dmw = (const float*)d_in[13];
  const float* dmb = (const float*)d_in[14];
  const float* dcw = (const float*)d_in[15];
  float* out = (float*)d_out;

  char* wsb = (char*)d_ws;
  __bf16* wb  = (__bf16*)wsb;
  __bf16* qnb = (__bf16*)(wsb + QNB_B);
  __bf16* dnb = (__bf16*)(wsb + DNB_B);
  float*  pkq = (float*)(wsb + PKQ_B);

  prep_kernel<<<960, 256, 0, stream>>>(w1, w2, w3, wb);
  conv_fused<<<dim3(9, kB), 256, 0, stream>>>(qe, de, wb, b1, b2, b3, qnb, dnb);
  pool_mfma<<<dim3(9, kB), 256, 0, stream>>>(qnb, dnb, qm, dm, pkq);
  finalize_kernel<<<kB, 128, 0, stream>>>(pkq, qm, dm, ns, dw, db, dmw, dmb, dcw, out);
}